// Round 4
// baseline (966.869 us; speedup 1.0000x reference)
//
#include <hip/hip_runtime.h>

#define RANK   32
#define DIM    128
#define BATCH  64           // rows gathered per wave-batch (one idx per lane)
#define GROUPS (BATCH / 8)  // global_load_lds ops per batch (8 rows / 1KB each)

// Round-4 fix: round 3 raced — the next batch's global_load_lds DMA writes
// were not ordered against the previous batch's outstanding broadcast ds_reads
// (compiler doesn't model the builtin's LDS write as aliasing them). Pre-timing
// absmax was 0.0; graph-replay timing exposed the race. Fix: drain lgkmcnt(0)
// BEFORE re-issuing DMA into the wave's buffer, and fence each waitcnt with
// sched_barrier(0) so nothing is scheduled across it (guide rule #18).
__global__ __launch_bounds__(256, 4) void lowrank_emb_kernel(
    const int* __restrict__ idx,
    const float* __restrict__ W1,
    const float* __restrict__ W2,
    float* __restrict__ out,
    int n_rows)
{
  __shared__ float lbuf[4][BATCH * RANK];  // 4 waves x 8KB = 32KB/block

  const int lane        = threadIdx.x & 63;
  const int waveInBlock = threadIdx.x >> 6;
  const int wavesPerBlk = blockDim.x >> 6;
  const int globalWave  = blockIdx.x * wavesPerBlk + waveInBlock;
  const int totalWaves  = gridDim.x * wavesPerBlk;

  float* wbuf = lbuf[waveInBlock];

  // Per-lane W2 column-pair slice, pinned in VGPRs (round-1 lesson: without
  // the opaque asm the compiler sinks these loads into the row loop).
  const int d = lane * 2;
  float2 w2r[RANK];
#pragma unroll
  for (int k = 0; k < RANK; ++k)
    w2r[k] = *reinterpret_cast<const float2*>(&W2[k * DIM + d]);
#pragma unroll
  for (int k = 0; k < RANK; ++k)
    asm("" : "+v"(w2r[k].x), "+v"(w2r[k].y));

  const int rsub  = lane >> 3;  // row within an 8-row gather group
  const int chunk = lane & 7;   // 16B chunk within the row

  const int nBatches = n_rows / BATCH;  // full batches; tail below
  for (int b = globalWave; b < nBatches; b += totalWaves) {
    const int rowBase = b * BATCH;

    // (1) Previous batch's ds_reads must retire before DMA overwrites LDS.
    asm volatile("s_waitcnt lgkmcnt(0)" ::: "memory");
    __builtin_amdgcn_sched_barrier(0);

    // One coalesced idx load: lane l carries idx[rowBase + l].
    const int iv = idx[rowBase + lane];

    // (2) Issue the gather: GROUPS x 1KB DMA-to-LDS, all in flight together.
    // Lane l fetches 16B chunk (l&7) of row (l>>3); HW writes base + l*16,
    // which is exactly row-major [8][32] floats.
#pragma unroll
    for (int g = 0; g < GROUPS; ++g) {
      const int e = __shfl(iv, g * 8 + rsub, 64);
      const float* src = W1 + (size_t)e * RANK + chunk * 4;
      __builtin_amdgcn_global_load_lds(
          (const __attribute__((address_space(1))) unsigned*)src,
          (__attribute__((address_space(3))) unsigned*)(wbuf + g * (8 * RANK)),
          16, 0, 0);
    }

    // (3) Wait for the DMA to land; fence so no ds_read hoists above.
    asm volatile("s_waitcnt vmcnt(0)" ::: "memory");
    __builtin_amdgcn_sched_barrier(0);

    // (4) Compute: per row, 8 broadcast (conflict-free) ds_read_b128 feeding
    // 64 v_fmac against the register-pinned W2 slice; 512B coalesced store.
#pragma unroll 2
    for (int r = 0; r < BATCH; ++r) {
      const float4* rowp = reinterpret_cast<const float4*>(wbuf + r * RANK);
      float a0 = 0.f, a1 = 0.f;
#pragma unroll
      for (int c = 0; c < 8; ++c) {
        const float4 f = rowp[c];
        a0 = fmaf(f.x, w2r[4 * c + 0].x, a0); a1 = fmaf(f.x, w2r[4 * c + 0].y, a1);
        a0 = fmaf(f.y, w2r[4 * c + 1].x, a0); a1 = fmaf(f.y, w2r[4 * c + 1].y, a1);
        a0 = fmaf(f.z, w2r[4 * c + 2].x, a0); a1 = fmaf(f.z, w2r[4 * c + 2].y, a1);
        a0 = fmaf(f.w, w2r[4 * c + 3].x, a0); a1 = fmaf(f.w, w2r[4 * c + 3].y, a1);
      }
      *reinterpret_cast<float2*>(&out[(size_t)(rowBase + r) * DIM + d]) =
          make_float2(a0, a1);
    }
  }

  // Tail rows (n_rows % BATCH; empty at 819200): scalar-uniform path.
  for (int row = nBatches * BATCH + globalWave; row < n_rows; row += totalWaves) {
    const int e = __builtin_amdgcn_readfirstlane(idx[row]);
    const float* __restrict__ p = W1 + (size_t)e * RANK;
    float a0 = 0.f, a1 = 0.f;
#pragma unroll
    for (int k = 0; k < RANK; ++k) {
      const float w = p[k];
      a0 = fmaf(w, w2r[k].x, a0);
      a1 = fmaf(w, w2r[k].y, a1);
    }
    *reinterpret_cast<float2*>(&out[(size_t)row * DIM + d]) = make_float2(a0, a1);
  }
}

extern "C" void kernel_launch(void* const* d_in, const int* in_sizes, int n_in,
                              void* d_out, int out_size, void* d_ws, size_t ws_size,
                              hipStream_t stream) {
  const int*   idx = (const int*)d_in[0];   // [4096*200]
  const float* W1  = (const float*)d_in[1]; // [1e6, 32]
  const float* W2  = (const float*)d_in[2]; // [32, 128]
  float*       out = (float*)d_out;         // [4096*200, 128]
  const int n_rows = in_sizes[0];

  const int threads = 256;   // 4 waves/block
  const int blocks  = 1024;  // 4 blocks/CU resident; grid-stride over batches
  hipLaunchKernelGGL(lowrank_emb_kernel, dim3(blocks), dim3(threads), 0, stream,
                     idx, W1, W2, out, n_rows);
}

// Round 5
// 145.689 us; speedup vs baseline: 6.6365x; 6.6365x over previous
//
#include <hip/hip_runtime.h>

#define RANK  32
#define DIM   128
#define BATCH 64            // rows per BLOCK-level batch
#define GROUPS (BATCH / 8)  // 8 global_load_lds ops (8 rows / 1KB each)

// Round-5 restructure. Round 4 proved the allocator will NOT keep a 64-float
// per-lane W2 slice resident (VGPR_Count=64 with w2r spilled to scratch ->
// 2.25GB of HBM spill traffic). Fix: halve the per-lane slice. The batch is
// now BLOCK-level: 4 waves share one 64-row LDS buffer; wave (dhalf=w&1)
// covers dims [dhalf*64, +64) with ONE dim per lane (w2r = 32 floats), wave
// (rhalf=w>>1) covers rows [rhalf*32, +32). Total register need ~56 -> fits
// the 64-VGPR / 8-waves-per-SIMD occupancy class with zero spills
// (__launch_bounds__(256,8) pins that budget).
__global__ __launch_bounds__(256, 8) void lowrank_emb_kernel(
    const int* __restrict__ idx,
    const float* __restrict__ W1,
    const float* __restrict__ W2,
    float* __restrict__ out,
    int n_rows)
{
  __shared__ float bbuf[BATCH * RANK];  // 8KB, shared by all 4 waves

  const int lane        = threadIdx.x & 63;
  const int waveInBlock = threadIdx.x >> 6;
  const int dhalf       = waveInBlock & 1;   // which 64-dim half
  const int rhalf       = waveInBlock >> 1;  // which 32-row half
  const int dim         = dhalf * 64 + lane; // this lane's output dim

  // Per-lane W2 column: w2r[k] = W2[k][dim]. 32 VGPRs. One-time strided load
  // (L2-resident). Pin after load to block rematerialization into the loop.
  float w2r[RANK];
#pragma unroll
  for (int k = 0; k < RANK; ++k) w2r[k] = W2[k * DIM + dim];
#pragma unroll
  for (int k = 0; k < RANK; ++k) asm("" : "+v"(w2r[k]));

  const int rsub  = lane >> 3;  // row within an 8-row gather group
  const int chunk = lane & 7;   // 16B chunk within a row

  const int nBatches = (n_rows + BATCH - 1) / BATCH;
  const int nBlocks  = gridDim.x;

  for (int b = blockIdx.x; b < nBatches; b += nBlocks) {
    const int rowBase = b * BATCH;

    // All waves must be done reading bbuf before we overwrite it.
    __syncthreads();

    // Coalesced idx load (each wave loads the same 64 -> L1 broadcast).
    const int myRow = rowBase + lane;
    const int iv = idx[myRow < n_rows ? myRow : (n_rows - 1)];

    // This wave issues 2 of the block's 8 gather groups: 8 rows / 1KB each.
    // Lane l fetches 16B chunk (l&7) of group-row (l>>3); HW writes
    // base + l*16, i.e. row-major [8][32] floats.
#pragma unroll
    for (int gi = 0; gi < GROUPS / 4; ++gi) {
      const int g = waveInBlock * (GROUPS / 4) + gi;
      const int e = __shfl(iv, g * 8 + rsub, 64);
      const float* src = W1 + (size_t)e * RANK + chunk * 4;
      __builtin_amdgcn_global_load_lds(
          (const __attribute__((address_space(1))) unsigned*)src,
          (__attribute__((address_space(3))) unsigned*)(bbuf + g * (8 * RANK)),
          16, 0, 0);
    }
    // Drain MY gathers (each wave drains its own before the barrier).
    asm volatile("s_waitcnt vmcnt(0)" ::: "memory");
    __builtin_amdgcn_sched_barrier(0);
    __syncthreads();  // now the whole 64-row batch is visible to all waves

    // Compute my 32 rows x my 64-dim half. Per row: 8 broadcast (same-address,
    // conflict-free) ds_read_b128 + 32 FMAs + one 256B coalesced store.
    const int r0 = rhalf * 32;
#pragma unroll 2
    for (int r = 0; r < 32; ++r) {
      const int rr = r0 + r;
      const float4* rowp = reinterpret_cast<const float4*>(bbuf + rr * RANK);
      float a0 = 0.f, a1 = 0.f;  // two accumulators to break the FMA chain
#pragma unroll
      for (int c = 0; c < 8; ++c) {
        const float4 f = rowp[c];
        a0 = fmaf(f.x, w2r[4 * c + 0], a0);
        a1 = fmaf(f.y, w2r[4 * c + 1], a1);
        a0 = fmaf(f.z, w2r[4 * c + 2], a0);
        a1 = fmaf(f.w, w2r[4 * c + 3], a1);
      }
      const int orow = rowBase + rr;
      if (orow < n_rows)
        out[(size_t)orow * DIM + dim] = a0 + a1;
    }
  }
}

extern "C" void kernel_launch(void* const* d_in, const int* in_sizes, int n_in,
                              void* d_out, int out_size, void* d_ws, size_t ws_size,
                              hipStream_t stream) {
  const int*   idx = (const int*)d_in[0];   // [4096*200]
  const float* W1  = (const float*)d_in[1]; // [1e6, 32]
  const float* W2  = (const float*)d_in[2]; // [32, 128]
  float*       out = (float*)d_out;         // [4096*200, 128]
  const int n_rows = in_sizes[0];

  const int threads = 256;   // 4 waves/block
  const int blocks  = 2048;  // target 8 blocks/CU resident; grid-stride batches
  hipLaunchKernelGGL(lowrank_emb_kernel, dim3(blocks), dim3(threads), 0, stream,
                     idx, W1, W2, out, n_rows);
}